// Round 4
// baseline (99.800 us; speedup 1.0000x reference)
//
#include <hip/hip_runtime.h>
#include <float.h>

// NearestCluster: per-batch NN argmin.
// coords1 [L1=4096, N=8, C=3] f32 (reference), coords2 [L2=4096, N=8, C=3] f32 (query)
// out int32: [L2*N] argmin idx over L1 per batch, then [L2*N] batch idx.
//
// Numerics: bit-exact vs numpy f32 reference:
//   qq = (q0*q0 + q1*q1) + q2*q2         rr likewise (round each op, no fma)
//   dot = ((q0*r0) + (q1*r1)) + (q2*r2)
//   d2 = (qq + rr) - 2*dot  ==  fma(-2, dot, qq+rr)   (2*dot exact)
// v_pk_{mul,add,fma}_f32 round each 32-bit half exactly like the scalar op.
// Ties -> lowest index (np.argmin first occurrence).
//
// R4 post-mortem: monolithic 7-inst asm blocks serialized the dep chains
// (VALUBusy 46%, 52us) and op_sel/float3 paths broke exactness (absmax 16).
// R5: per-op asm pk instructions (scheduler-visible), SoA ref-pairs in LDS so
// no op_sel broadcast is needed, scalar staging loads (R1-proven), 4-ref
// min-tournament tracking iteration tg only; winning k resolved in epilogue by
// first-occurrence argmin over exact SCALAR recompute (self-healing).
// Index order: candidate j = (tg*64+lane)*4 + k; blocks disjoint ascending in
// sel = tg*64+lane, so merging by (d, sel) + lowest-k-in-block is exact
// first-occurrence semantics.

typedef float v2f __attribute__((ext_vector_type(2)));

constexpr int kL1 = 4096, kL2 = 4096, kN = 8;
constexpr int kChunk = 1024;      // refs per LDS chunk -> 16 KB SoA
constexpr int kQPerBlock = 16;    // 4 waves x 4 queries
constexpr int kQ = 4;             // queries per wave

__device__ __forceinline__ v2f pk_mul(v2f a, v2f b) {
  v2f d; asm("v_pk_mul_f32 %0, %1, %2" : "=v"(d) : "v"(a), "v"(b)); return d;
}
__device__ __forceinline__ v2f pk_add(v2f a, v2f b) {
  v2f d; asm("v_pk_add_f32 %0, %1, %2" : "=v"(d) : "v"(a), "v"(b)); return d;
}
__device__ __forceinline__ v2f pk_fma(v2f a, v2f b, v2f c) {
  v2f d; asm("v_pk_fma_f32 %0, %1, %2, %3" : "=v"(d) : "v"(a), "v"(b), "v"(c)); return d;
}

// d2 for one query (duplicated pair) vs a ref PAIR in SoA form.
__device__ __forceinline__ v2f dist2_pair(v2f qx, v2f qy, v2f qz, v2f qq,
                                          v2f rx, v2f ry, v2f rz, v2f rr, v2f n2) {
  const v2f s01 = pk_add(pk_mul(qx, rx), pk_mul(qy, ry));
  const v2f dot = pk_add(s01, pk_mul(qz, rz));
  const v2f A = pk_add(qq, rr);
  return pk_fma(dot, n2, A);
}

__global__ __launch_bounds__(256, 4)
void nearest_kernel(const float* __restrict__ c1, const float* __restrict__ c2,
                    int* __restrict__ out) {
#pragma clang fp contract(off)
  // SoA: ref j (within chunk) at component arrays; j = w*4+k staged by thread w.
  __shared__ float sRx[kChunk], sRy[kChunk], sRz[kChunk], sRr[kChunk];

  const int tid = threadIdx.x;
  const int n = blockIdx.y;
  const int wave = tid >> 6;
  const int lane = tid & 63;
  const int q0 = blockIdx.x * kQPerBlock + wave * kQ;

  // 4 queries per wave; each scalar duplicated into a v2f pair (loop-invariant).
  float qxs[kQ], qys[kQ], qzs[kQ], qqs[kQ];
  v2f qx2[kQ], qy2[kQ], qz2[kQ], qq2[kQ];
#pragma unroll
  for (int i = 0; i < kQ; ++i) {
    const float* p = c2 + ((q0 + i) * kN + n) * 3;
    qxs[i] = p[0]; qys[i] = p[1]; qzs[i] = p[2];
    qqs[i] = __fadd_rn(__fadd_rn(__fmul_rn(qxs[i], qxs[i]), __fmul_rn(qys[i], qys[i])),
                       __fmul_rn(qzs[i], qzs[i]));
    qx2[i] = (v2f){qxs[i], qxs[i]};
    qy2[i] = (v2f){qys[i], qys[i]};
    qz2[i] = (v2f){qzs[i], qzs[i]};
    qq2[i] = (v2f){qqs[i], qqs[i]};
  }
  const v2f n2 = {-2.0f, -2.0f};

  float bd[kQ]; int bt[kQ];
#pragma unroll
  for (int i = 0; i < kQ; ++i) { bd[i] = FLT_MAX; bt[i] = 0; }

  for (int chunk = 0; chunk < kL1 / kChunk; ++chunk) {
    __syncthreads();  // previous chunk's readers done before overwrite

    // ---- Stage: thread w loads refs jb..jb+3 (scalar loads, R1-proven),
    //      writes SoA via one ds_write_b128 per component (conflict-free).
    {
      const int jb = chunk * kChunk + tid * 4;
      float x[4], y[4], z[4], w4[4];
#pragma unroll
      for (int k = 0; k < 4; ++k) {
        const float* p = c1 + ((jb + k) * kN + n) * 3;
        x[k] = p[0]; y[k] = p[1]; z[k] = p[2];
        w4[k] = __fadd_rn(__fadd_rn(__fmul_rn(x[k], x[k]), __fmul_rn(y[k], y[k])),
                          __fmul_rn(z[k], z[k]));
      }
      *reinterpret_cast<float4*>(&sRx[tid * 4]) = make_float4(x[0], x[1], x[2], x[3]);
      *reinterpret_cast<float4*>(&sRy[tid * 4]) = make_float4(y[0], y[1], y[2], y[3]);
      *reinterpret_cast<float4*>(&sRz[tid * 4]) = make_float4(z[0], z[1], z[2], z[3]);
      *reinterpret_cast<float4*>(&sRr[tid * 4]) = make_float4(w4[0], w4[1], w4[2], w4[3]);
    }
    __syncthreads();

#pragma unroll
    for (int t = 0; t < kChunk / 256; ++t) {  // 4 iters/chunk, 256 refs/iter
      const int tg = chunk * (kChunk / 256) + t;
      const int base = t * 256 + lane * 4;
      const float4 rx4 = *reinterpret_cast<const float4*>(&sRx[base]);
      const float4 ry4 = *reinterpret_cast<const float4*>(&sRy[base]);
      const float4 rz4 = *reinterpret_cast<const float4*>(&sRz[base]);
      const float4 rr4 = *reinterpret_cast<const float4*>(&sRr[base]);
      const v2f rx01 = {rx4.x, rx4.y}, rx23 = {rx4.z, rx4.w};
      const v2f ry01 = {ry4.x, ry4.y}, ry23 = {ry4.z, ry4.w};
      const v2f rz01 = {rz4.x, rz4.y}, rz23 = {rz4.z, rz4.w};
      const v2f rr01 = {rr4.x, rr4.y}, rr23 = {rr4.z, rr4.w};

#pragma unroll
      for (int i = 0; i < kQ; ++i) {
        const v2f d01 = dist2_pair(qx2[i], qy2[i], qz2[i], qq2[i],
                                   rx01, ry01, rz01, rr01, n2);
        const v2f d23 = dist2_pair(qx2[i], qy2[i], qz2[i], qq2[i],
                                   rx23, ry23, rz23, rr23, n2);
        const float old = bd[i];
        float m = fminf(fminf(d01.x, d01.y), old);     // -> v_min3_f32
        m = fminf(fminf(d23.x, d23.y), m);             // -> v_min3_f32
        bd[i] = m;
        if (m < old) bt[i] = tg;                       // cmp + cndmask
      }
    }
  }

  // ---- Cross-lane merge on (d, sel) with sel = bt*64+lane (index-aware).
  int sel[kQ];
#pragma unroll
  for (int i = 0; i < kQ; ++i) sel[i] = bt[i] * 64 + lane;
#pragma unroll
  for (int m = 1; m <= 32; m <<= 1) {
#pragma unroll
    for (int i = 0; i < kQ; ++i) {
      const float od = __shfl_xor(bd[i], m);
      const int os = __shfl_xor(sel[i], m);
      if (od < bd[i] || (od == bd[i] && os < sel[i])) { bd[i] = od; sel[i] = os; }
    }
  }

  // ---- Epilogue: resolve k within the winning 4-block by first-occurrence
  //      argmin over an exact scalar recompute (independent of pk bits).
#pragma unroll
  for (int i = 0; i < kQ; ++i) {
    if (lane == i) {
      const int j0 = sel[i] * 4;
      float best = FLT_MAX; int kk = 0;
#pragma unroll
      for (int k = 0; k < 4; ++k) {
        const float* p = c1 + ((j0 + k) * kN + n) * 3;
        const float r0 = p[0], r1 = p[1], r2 = p[2];
        const float rr = __fadd_rn(
            __fadd_rn(__fmul_rn(r0, r0), __fmul_rn(r1, r1)), __fmul_rn(r2, r2));
        const float dot = __fadd_rn(
            __fadd_rn(__fmul_rn(qxs[i], r0), __fmul_rn(qys[i], r1)),
            __fmul_rn(qzs[i], r2));
        const float dc = __fmaf_rn(-2.0f, dot, __fadd_rn(qqs[i], rr));
        if (dc < best) { best = dc; kk = k; }
      }
      out[(q0 + i) * kN + n] = j0 + kk;
      out[kL2 * kN + (q0 + i) * kN + n] = n;
    }
  }
}

extern "C" void kernel_launch(void* const* d_in, const int* in_sizes, int n_in,
                              void* d_out, int out_size, void* d_ws, size_t ws_size,
                              hipStream_t stream) {
  const float* c1 = (const float*)d_in[0];
  const float* c2 = (const float*)d_in[1];
  int* out = (int*)d_out;
  dim3 grid(kL2 / kQPerBlock, kN);  // 256 x 8 = 2048 blocks
  nearest_kernel<<<grid, dim3(256), 0, stream>>>(c1, c2, out);
}

// Round 5
// 90.071 us; speedup vs baseline: 1.1080x; 1.1080x over previous
//
#include <hip/hip_runtime.h>
#include <float.h>

// NearestCluster: per-batch NN argmin.
// coords1 [L1=4096, N=8, C=3] f32 (reference), coords2 [L2=4096, N=8, C=3] f32 (query)
// out int32: [L2*N] argmin idx over L1 per batch, then [L2*N] batch idx.
//
// Numerics: bit-exact vs numpy f32 reference:
//   qq = (q0*q0 + q1*q1) + q2*q2         rr likewise (round each op, no fma)
//   dot = ((q0*r0) + (q1*r1)) + (q2*r2)
//   d2 = (qq + rr) - 2*dot  ==  fma(-2, dot, qq+rr)   (2*dot exact)
// Ties -> lowest index (np.argmin first occurrence).
//
// R4/R5 post-mortem: all "fewer instructions via inline-asm pk" attempts LOST
// (marshalling movs + scheduler blindness); compiler-scheduled scalar math is
// the local optimum. The real non-scaling cost: per-block barrier-serialized
// staging with 12B@96B-stride gathers of c1, paid by all 2048 blocks, plus LDS
// waitcnt chains. R6: kernel1 transposes c1 once into per-batch SoA
// (X[n][4096],Y,Z,RR in ws, 512KB, coalesced read, rr computed once); kernel2
// has NO LDS and NO barriers -- lanes stream 4 refs/component via coalesced
// dwordx4 loads from the L2-resident SoA, compiler pipelines loads freely.
// Math: R5's verified scalar chain + 4-ref min3 tournament (track iteration t
// only; j = sel*4+k; k resolved in epilogue by exact first-occurrence
// recompute). Fallback to the verified R5 LDS kernel if ws is too small.

constexpr int kL1 = 4096, kL2 = 4096, kN = 8;
constexpr int kQPerBlock = 16;    // 4 waves x 4 queries
constexpr int kQ = 4;             // queries per wave
constexpr int kSoAFloats = kN * kL1;              // per component
constexpr size_t kWsBytes = 4ull * kSoAFloats * sizeof(float);  // 512 KB

// ---------------- Kernel 1: c1 -> per-batch SoA with exact rr ----------------
__global__ __launch_bounds__(256)
void soa_kernel(const float* __restrict__ c1, float* __restrict__ ws) {
#pragma clang fp contract(off)
  const int t = blockIdx.x * 256 + threadIdx.x;   // 0 .. L1*N-1
  const int n = t & (kN - 1);
  const int j = t >> 3;
  const float* p = c1 + t * 3;                    // (j*kN+n)*3 == t*3 (coalesced)
  const float x = p[0], y = p[1], z = p[2];
  const float rr = __fadd_rn(
      __fadd_rn(__fmul_rn(x, x), __fmul_rn(y, y)), __fmul_rn(z, z));
  const int o = n * kL1 + j;
  ws[o] = x;
  ws[kSoAFloats + o] = y;
  ws[2 * kSoAFloats + o] = z;
  ws[3 * kSoAFloats + o] = rr;
}

// ---------------- Kernel 2: barrier-free streaming argmin ----------------
__global__ __launch_bounds__(256, 4)
void nearest_soa_kernel(const float* __restrict__ ws, const float* __restrict__ c2,
                        int* __restrict__ out) {
#pragma clang fp contract(off)
  const int n = blockIdx.y;
  const int wave = threadIdx.x >> 6;
  const int lane = threadIdx.x & 63;
  const int q0 = blockIdx.x * kQPerBlock + wave * kQ;

  const float* __restrict__ X = ws + n * kL1;
  const float* __restrict__ Y = ws + kSoAFloats + n * kL1;
  const float* __restrict__ Z = ws + 2 * kSoAFloats + n * kL1;
  const float* __restrict__ RR = ws + 3 * kSoAFloats + n * kL1;

  float qx[kQ], qy[kQ], qz[kQ], qq[kQ];
#pragma unroll
  for (int i = 0; i < kQ; ++i) {
    const float* p = c2 + ((q0 + i) * kN + n) * 3;
    qx[i] = p[0]; qy[i] = p[1]; qz[i] = p[2];
    qq[i] = __fadd_rn(__fadd_rn(__fmul_rn(qx[i], qx[i]), __fmul_rn(qy[i], qy[i])),
                      __fmul_rn(qz[i], qz[i]));
  }

  float bd[kQ]; int bt[kQ];
#pragma unroll
  for (int i = 0; i < kQ; ++i) { bd[i] = FLT_MAX; bt[i] = 0; }

#pragma unroll 2
  for (int t = 0; t < kL1 / 256; ++t) {  // 16 iters; lane handles refs b..b+3
    const int b = t * 256 + lane * 4;
    const float4 x4 = *reinterpret_cast<const float4*>(X + b);
    const float4 y4 = *reinterpret_cast<const float4*>(Y + b);
    const float4 z4 = *reinterpret_cast<const float4*>(Z + b);
    const float4 r4 = *reinterpret_cast<const float4*>(RR + b);
    const float xs[4] = {x4.x, x4.y, x4.z, x4.w};
    const float ys[4] = {y4.x, y4.y, y4.z, y4.w};
    const float zs[4] = {z4.x, z4.y, z4.z, z4.w};
    const float rs[4] = {r4.x, r4.y, r4.z, r4.w};

#pragma unroll
    for (int i = 0; i < kQ; ++i) {
      float d[4];
#pragma unroll
      for (int k = 0; k < 4; ++k) {
        const float dot = __fadd_rn(
            __fadd_rn(__fmul_rn(qx[i], xs[k]), __fmul_rn(qy[i], ys[k])),
            __fmul_rn(qz[i], zs[k]));
        d[k] = __fmaf_rn(-2.0f, dot, __fadd_rn(qq[i], rs[k]));
      }
      const float old = bd[i];
      float m = fminf(fminf(d[0], d[1]), old);   // -> v_min3_f32
      m = fminf(fminf(d[2], d[3]), m);           // -> v_min3_f32
      bd[i] = m;
      if (m < old) bt[i] = t;                    // cmp + cndmask
    }
  }

  // ---- Cross-lane merge on (d, sel), sel = bt*64+lane; candidate j = sel*4+k,
  //      blocks disjoint ascending in sel -> exact first-occurrence semantics.
  int sel[kQ];
#pragma unroll
  for (int i = 0; i < kQ; ++i) sel[i] = bt[i] * 64 + lane;
#pragma unroll
  for (int m = 1; m <= 32; m <<= 1) {
#pragma unroll
    for (int i = 0; i < kQ; ++i) {
      const float od = __shfl_xor(bd[i], m);
      const int os = __shfl_xor(sel[i], m);
      if (od < bd[i] || (od == bd[i] && os < sel[i])) { bd[i] = od; sel[i] = os; }
    }
  }

  // ---- Epilogue: resolve k within the winning 4-block by first-occurrence
  //      argmin over an exact scalar recompute from the same SoA bits.
#pragma unroll
  for (int i = 0; i < kQ; ++i) {
    if (lane == i) {
      const int j0 = sel[i] * 4;
      float best = FLT_MAX; int kk = 0;
#pragma unroll
      for (int k = 0; k < 4; ++k) {
        const float dot = __fadd_rn(
            __fadd_rn(__fmul_rn(qx[i], X[j0 + k]), __fmul_rn(qy[i], Y[j0 + k])),
            __fmul_rn(qz[i], Z[j0 + k]));
        const float dc = __fmaf_rn(-2.0f, dot, __fadd_rn(qq[i], RR[j0 + k]));
        if (dc < best) { best = dc; kk = k; }
      }
      out[(q0 + i) * kN + n] = j0 + kk;
      out[kL2 * kN + (q0 + i) * kN + n] = n;
    }
  }
}

// ---------------- Fallback (verified R5): LDS staging, used if ws too small ----
typedef float v2f __attribute__((ext_vector_type(2)));
constexpr int kChunk = 1024;

__global__ __launch_bounds__(256, 4)
void nearest_kernel_lds(const float* __restrict__ c1, const float* __restrict__ c2,
                        int* __restrict__ out) {
#pragma clang fp contract(off)
  __shared__ float sRx[kChunk], sRy[kChunk], sRz[kChunk], sRr[kChunk];
  const int tid = threadIdx.x;
  const int n = blockIdx.y;
  const int wave = tid >> 6;
  const int lane = tid & 63;
  const int q0 = blockIdx.x * kQPerBlock + wave * kQ;

  float qxs[kQ], qys[kQ], qzs[kQ], qqs[kQ];
#pragma unroll
  for (int i = 0; i < kQ; ++i) {
    const float* p = c2 + ((q0 + i) * kN + n) * 3;
    qxs[i] = p[0]; qys[i] = p[1]; qzs[i] = p[2];
    qqs[i] = __fadd_rn(__fadd_rn(__fmul_rn(qxs[i], qxs[i]), __fmul_rn(qys[i], qys[i])),
                       __fmul_rn(qzs[i], qzs[i]));
  }

  float bd[kQ]; int bt[kQ];
#pragma unroll
  for (int i = 0; i < kQ; ++i) { bd[i] = FLT_MAX; bt[i] = 0; }

  for (int chunk = 0; chunk < kL1 / kChunk; ++chunk) {
    __syncthreads();
    {
      const int jb = chunk * kChunk + tid * 4;
      float x[4], y[4], z[4], w4[4];
#pragma unroll
      for (int k = 0; k < 4; ++k) {
        const float* p = c1 + ((jb + k) * kN + n) * 3;
        x[k] = p[0]; y[k] = p[1]; z[k] = p[2];
        w4[k] = __fadd_rn(__fadd_rn(__fmul_rn(x[k], x[k]), __fmul_rn(y[k], y[k])),
                          __fmul_rn(z[k], z[k]));
      }
      *reinterpret_cast<float4*>(&sRx[tid * 4]) = make_float4(x[0], x[1], x[2], x[3]);
      *reinterpret_cast<float4*>(&sRy[tid * 4]) = make_float4(y[0], y[1], y[2], y[3]);
      *reinterpret_cast<float4*>(&sRz[tid * 4]) = make_float4(z[0], z[1], z[2], z[3]);
      *reinterpret_cast<float4*>(&sRr[tid * 4]) = make_float4(w4[0], w4[1], w4[2], w4[3]);
    }
    __syncthreads();

#pragma unroll
    for (int t = 0; t < kChunk / 256; ++t) {
      const int tg = chunk * (kChunk / 256) + t;
      const int base = t * 256 + lane * 4;
      const float4 x4 = *reinterpret_cast<const float4*>(&sRx[base]);
      const float4 y4 = *reinterpret_cast<const float4*>(&sRy[base]);
      const float4 z4 = *reinterpret_cast<const float4*>(&sRz[base]);
      const float4 r4 = *reinterpret_cast<const float4*>(&sRr[base]);
      const float xs[4] = {x4.x, x4.y, x4.z, x4.w};
      const float ys[4] = {y4.x, y4.y, y4.z, y4.w};
      const float zs[4] = {z4.x, z4.y, z4.z, z4.w};
      const float rs[4] = {r4.x, r4.y, r4.z, r4.w};
#pragma unroll
      for (int i = 0; i < kQ; ++i) {
        float d[4];
#pragma unroll
        for (int k = 0; k < 4; ++k) {
          const float dot = __fadd_rn(
              __fadd_rn(__fmul_rn(qxs[i], xs[k]), __fmul_rn(qys[i], ys[k])),
              __fmul_rn(qzs[i], zs[k]));
          d[k] = __fmaf_rn(-2.0f, dot, __fadd_rn(qqs[i], rs[k]));
        }
        const float old = bd[i];
        float m = fminf(fminf(d[0], d[1]), old);
        m = fminf(fminf(d[2], d[3]), m);
        bd[i] = m;
        if (m < old) bt[i] = tg;
      }
    }
  }

  int sel[kQ];
#pragma unroll
  for (int i = 0; i < kQ; ++i) sel[i] = bt[i] * 64 + lane;
#pragma unroll
  for (int m = 1; m <= 32; m <<= 1) {
#pragma unroll
    for (int i = 0; i < kQ; ++i) {
      const float od = __shfl_xor(bd[i], m);
      const int os = __shfl_xor(sel[i], m);
      if (od < bd[i] || (od == bd[i] && os < sel[i])) { bd[i] = od; sel[i] = os; }
    }
  }

#pragma unroll
  for (int i = 0; i < kQ; ++i) {
    if (lane == i) {
      const int j0 = sel[i] * 4;
      float best = FLT_MAX; int kk = 0;
#pragma unroll
      for (int k = 0; k < 4; ++k) {
        const float* p = c1 + ((j0 + k) * kN + n) * 3;
        const float r0 = p[0], r1 = p[1], r2 = p[2];
        const float rr = __fadd_rn(
            __fadd_rn(__fmul_rn(r0, r0), __fmul_rn(r1, r1)), __fmul_rn(r2, r2));
        const float dot = __fadd_rn(
            __fadd_rn(__fmul_rn(qxs[i], r0), __fmul_rn(qys[i], r1)),
            __fmul_rn(qzs[i], r2));
        const float dc = __fmaf_rn(-2.0f, dot, __fadd_rn(qqs[i], rr));
        if (dc < best) { best = dc; kk = k; }
      }
      out[(q0 + i) * kN + n] = j0 + kk;
      out[kL2 * kN + (q0 + i) * kN + n] = n;
    }
  }
}

extern "C" void kernel_launch(void* const* d_in, const int* in_sizes, int n_in,
                              void* d_out, int out_size, void* d_ws, size_t ws_size,
                              hipStream_t stream) {
  const float* c1 = (const float*)d_in[0];
  const float* c2 = (const float*)d_in[1];
  int* out = (int*)d_out;
  if (d_ws != nullptr && ws_size >= kWsBytes) {
    float* ws = (float*)d_ws;
    soa_kernel<<<dim3(kL1 * kN / 256), dim3(256), 0, stream>>>(c1, ws);
    dim3 grid(kL2 / kQPerBlock, kN);  // 256 x 8 = 2048 blocks
    nearest_soa_kernel<<<grid, dim3(256), 0, stream>>>(ws, c2, out);
  } else {
    dim3 grid(kL2 / kQPerBlock, kN);
    nearest_kernel_lds<<<grid, dim3(256), 0, stream>>>(c1, c2, out);
  }
}

// Round 6
// 85.875 us; speedup vs baseline: 1.1621x; 1.0489x over previous
//
#include <hip/hip_runtime.h>
#include <float.h>

// NearestCluster: per-batch NN argmin via uniform 8^3 grid (exact).
// coords1 [L1=4096, N=8, C=3] f32 (reference), coords2 [L2=4096, N=8, C=3] f32 (query)
// out int32: [L2*N] argmin idx over L1 per batch, then [L2*N] batch idx.
//
// Numerics: bit-exact vs numpy f32 reference:
//   qq = (q0*q0 + q1*q1) + q2*q2         rr likewise (round each op, no fma)
//   dot = ((q0*r0) + (q1*r1)) + (q2*r2)
//   d2 = (qq + rr) - 2*dot  ==  fma(-2, dot, qq+rr)   (2*dot exact)
// Ties -> lowest ORIGINAL index (np.argmin first occurrence), enforced in the
// scan update and in every merge.
//
// R1-R6 post-mortem: VALU-busy time ~26.5us invariant across all brute-force
// memory structures -> issue-bound on 134M x ~9 slots. Only an algorithmic cut
// helps. Data uniform in [0,1]^3 -> 8^3 grid: ~27 cells x ~8 pts = ~220 exact
// distances per query (19x fewer).
//
// Pruning exactness: ring lower bound lb = ((r-1)/8)^2 is EXACT in f32
// (k^2/64, k<=7). Points in ring >= r have true d^2 >= lb. Computed d2 differs
// from true by <= ~40eps*6 ~= 2.4e-6 (coords in [0,1]). Break only when
// lb > bd + 4e-6  =>  any pruned point's COMPUTED d2 > bd >= final min
// => pruned points are never the argmin nor a tie. All survivors are computed
// with the exact chain => identical result to full argmin.
//
// ws layout (672000 B; harness ws is ~268 MB):
//   int   cellStart[8][520]   (513 used: 512 cell starts + total)   16640 B
//   float4 pts[8][4096]       (x,y,z,rr) cell-ordered              524288 B
//   int   pidx[8][4096]       original ref index                   131072 B
// Fallback to the verified R5 LDS brute-force kernel if ws too small.

constexpr int kL1 = 4096, kL2 = 4096, kN = 8;
constexpr int kCS = 520;                       // ints per batch in cellStart
constexpr size_t kOffPts = 8ull * kCS * 4;                   // 16640
constexpr size_t kOffIdx = kOffPts + 8ull * kL1 * 16;        // 540928
constexpr size_t kWsBytes = kOffIdx + 8ull * kL1 * 4;        // 672000

__device__ __forceinline__ float rr_exact(float x, float y, float z) {
  return __fadd_rn(__fadd_rn(__fmul_rn(x, x), __fmul_rn(y, y)), __fmul_rn(z, z));
}

// ---------------- Kernel 1: bin refs into 8^3 cells per batch ----------------
__global__ __launch_bounds__(1024)
void bin_kernel(const float* __restrict__ c1, int* __restrict__ cellStart,
                float4* __restrict__ pts, int* __restrict__ pidx) {
#pragma clang fp contract(off)
  __shared__ int cnt[512];
  const int tid = threadIdx.x;
  const int n = blockIdx.x;
  if (tid < 512) cnt[tid] = 0;
  __syncthreads();

  float xs[4], ys[4], zs[4];
  int cl[4];
#pragma unroll
  for (int k = 0; k < 4; ++k) {
    const int j = k * 1024 + tid;
    const float* p = c1 + (j * kN + n) * 3;
    const float x = p[0], y = p[1], z = p[2];
    xs[k] = x; ys[k] = y; zs[k] = z;
    const int cx = min(7, max(0, (int)(x * 8.0f)));
    const int cy = min(7, max(0, (int)(y * 8.0f)));
    const int cz = min(7, max(0, (int)(z * 8.0f)));
    cl[k] = (cz * 8 + cy) * 8 + cx;
    atomicAdd(&cnt[cl[k]], 1);
  }
  __syncthreads();

  // Exclusive prefix over 512 counts: wave 0, 8 cells/lane + shfl scan.
  if (tid < 64) {
    int loc[8], part = 0;
#pragma unroll
    for (int i = 0; i < 8; ++i) { loc[i] = cnt[tid * 8 + i]; part += loc[i]; }
    int inc = part;
#pragma unroll
    for (int off = 1; off < 64; off <<= 1) {
      const int v = __shfl_up(inc, off);
      if (tid >= off) inc += v;
    }
    int base = inc - part;
#pragma unroll
    for (int i = 0; i < 8; ++i) {
      const int c = tid * 8 + i;
      cellStart[n * kCS + c] = base;
      cnt[c] = base;                 // becomes scatter cursor
      base += loc[i];
    }
    if (tid == 0) cellStart[n * kCS + 512] = kL1;
  }
  __syncthreads();

#pragma unroll
  for (int k = 0; k < 4; ++k) {
    const int j = k * 1024 + tid;
    const int pos = atomicAdd(&cnt[cl[k]], 1);
    pts[n * kL1 + pos] = make_float4(xs[k], ys[k], zs[k], rr_exact(xs[k], ys[k], zs[k]));
    pidx[n * kL1 + pos] = j;
  }
}

// ---------------- Kernel 2: expanding-ring exact NN, 8 lanes/query ----------------
__global__ __launch_bounds__(256, 8)
void grid_nn_kernel(const int* __restrict__ cellStart, const float4* __restrict__ pts,
                    const int* __restrict__ pidx, const float* __restrict__ c2,
                    int* __restrict__ out) {
#pragma clang fp contract(off)
  const int gid = blockIdx.x * 256 + threadIdx.x;
  const int query = gid >> 3;        // 0..32767
  const int sub = gid & 7;           // lane within 8-lane group (aligned)
  const int qj = query >> 3;         // L2 index
  const int n = query & 7;           // batch

  const float* p = c2 + (qj * kN + n) * 3;
  const float qx = p[0], qy = p[1], qz = p[2];
  const float qq = rr_exact(qx, qy, qz);
  const int cx = min(7, max(0, (int)(qx * 8.0f)));
  const int cy = min(7, max(0, (int)(qy * 8.0f)));
  const int cz = min(7, max(0, (int)(qz * 8.0f)));

  const int* __restrict__ cs = cellStart + n * kCS;
  const float4* __restrict__ P = pts + n * kL1;
  const int* __restrict__ I = pidx + n * kL1;

  float bd = FLT_MAX;
  int bi = 0x7FFFFFFF;

  for (int r = 0; r < 8; ++r) {
    if (r > 0) {
      const float t = (r - 1) * 0.125f;       // exact
      if (t * t > __fadd_rn(bd, 4e-6f)) break;  // margin covers d2 rounding
    }
    for (int dz = -r; dz <= r; ++dz) {
      const int z = cz + dz;
      if (z < 0 || z > 7) continue;
      const bool zf = (dz == r || dz == -r);
      for (int dy = -r; dy <= r; ++dy) {
        const int y = cy + dy;
        if (y < 0 || y > 7) continue;
        const bool zyf = zf || dy == r || dy == -r;
        for (int dx = -r; dx <= r; ++dx) {
          if (!zyf && dx != r && dx != -r) continue;  // Chebyshev shell == r
          const int x = cx + dx;
          if (x < 0 || x > 7) continue;
          const int c = (z * 8 + y) * 8 + x;
          const int s = cs[c], e = cs[c + 1];
          for (int pp = s + sub; pp < e; pp += 8) {
            const float4 rp = P[pp];
            const int id = I[pp];
            const float dot = __fadd_rn(
                __fadd_rn(__fmul_rn(qx, rp.x), __fmul_rn(qy, rp.y)),
                __fmul_rn(qz, rp.z));
            const float d2 = __fmaf_rn(-2.0f, dot, __fadd_rn(qq, rp.w));
            if (d2 < bd || (d2 == bd && id < bi)) { bd = d2; bi = id; }
          }
        }
      }
    }
    // merge (bd,bi) across the aligned 8-lane group -> tighter bound next ring
#pragma unroll
    for (int m = 1; m <= 4; m <<= 1) {
      const float od = __shfl_xor(bd, m);
      const int oi = __shfl_xor(bi, m);
      if (od < bd || (od == bd && oi < bi)) { bd = od; bi = oi; }
    }
  }

  if (sub == 0) {
    out[qj * kN + n] = bi;
    out[kL2 * kN + qj * kN + n] = n;
  }
}

// ---------------- Fallback (verified R5/R6 brute force, LDS) ----------------
constexpr int kQPerBlock = 16;
constexpr int kQ = 4;
constexpr int kChunk = 1024;

__global__ __launch_bounds__(256, 4)
void nearest_kernel_lds(const float* __restrict__ c1, const float* __restrict__ c2,
                        int* __restrict__ out) {
#pragma clang fp contract(off)
  __shared__ float sRx[kChunk], sRy[kChunk], sRz[kChunk], sRr[kChunk];
  const int tid = threadIdx.x;
  const int n = blockIdx.y;
  const int wave = tid >> 6;
  const int lane = tid & 63;
  const int q0 = blockIdx.x * kQPerBlock + wave * kQ;

  float qxs[kQ], qys[kQ], qzs[kQ], qqs[kQ];
#pragma unroll
  for (int i = 0; i < kQ; ++i) {
    const float* p = c2 + ((q0 + i) * kN + n) * 3;
    qxs[i] = p[0]; qys[i] = p[1]; qzs[i] = p[2];
    qqs[i] = rr_exact(qxs[i], qys[i], qzs[i]);
  }
  float bd[kQ]; int bt[kQ];
#pragma unroll
  for (int i = 0; i < kQ; ++i) { bd[i] = FLT_MAX; bt[i] = 0; }

  for (int chunk = 0; chunk < kL1 / kChunk; ++chunk) {
    __syncthreads();
    {
      const int jb = chunk * kChunk + tid * 4;
      float x[4], y[4], z[4], w4[4];
#pragma unroll
      for (int k = 0; k < 4; ++k) {
        const float* p = c1 + ((jb + k) * kN + n) * 3;
        x[k] = p[0]; y[k] = p[1]; z[k] = p[2];
        w4[k] = rr_exact(x[k], y[k], z[k]);
      }
      *reinterpret_cast<float4*>(&sRx[tid * 4]) = make_float4(x[0], x[1], x[2], x[3]);
      *reinterpret_cast<float4*>(&sRy[tid * 4]) = make_float4(y[0], y[1], y[2], y[3]);
      *reinterpret_cast<float4*>(&sRz[tid * 4]) = make_float4(z[0], z[1], z[2], z[3]);
      *reinterpret_cast<float4*>(&sRr[tid * 4]) = make_float4(w4[0], w4[1], w4[2], w4[3]);
    }
    __syncthreads();
#pragma unroll
    for (int t = 0; t < kChunk / 256; ++t) {
      const int tg = chunk * (kChunk / 256) + t;
      const int base = t * 256 + lane * 4;
      const float4 x4 = *reinterpret_cast<const float4*>(&sRx[base]);
      const float4 y4 = *reinterpret_cast<const float4*>(&sRy[base]);
      const float4 z4 = *reinterpret_cast<const float4*>(&sRz[base]);
      const float4 r4 = *reinterpret_cast<const float4*>(&sRr[base]);
      const float xs[4] = {x4.x, x4.y, x4.z, x4.w};
      const float ys[4] = {y4.x, y4.y, y4.z, y4.w};
      const float zs[4] = {z4.x, z4.y, z4.z, z4.w};
      const float rs[4] = {r4.x, r4.y, r4.z, r4.w};
#pragma unroll
      for (int i = 0; i < kQ; ++i) {
        float d[4];
#pragma unroll
        for (int k = 0; k < 4; ++k) {
          const float dot = __fadd_rn(
              __fadd_rn(__fmul_rn(qxs[i], xs[k]), __fmul_rn(qys[i], ys[k])),
              __fmul_rn(qzs[i], zs[k]));
          d[k] = __fmaf_rn(-2.0f, dot, __fadd_rn(qqs[i], rs[k]));
        }
        const float old = bd[i];
        float m = fminf(fminf(d[0], d[1]), old);
        m = fminf(fminf(d[2], d[3]), m);
        bd[i] = m;
        if (m < old) bt[i] = tg;
      }
    }
  }
  int sel[kQ];
#pragma unroll
  for (int i = 0; i < kQ; ++i) sel[i] = bt[i] * 64 + lane;
#pragma unroll
  for (int m = 1; m <= 32; m <<= 1) {
#pragma unroll
    for (int i = 0; i < kQ; ++i) {
      const float od = __shfl_xor(bd[i], m);
      const int os = __shfl_xor(sel[i], m);
      if (od < bd[i] || (od == bd[i] && os < sel[i])) { bd[i] = od; sel[i] = os; }
    }
  }
#pragma unroll
  for (int i = 0; i < kQ; ++i) {
    if (lane == i) {
      const int j0 = sel[i] * 4;
      float best = FLT_MAX; int kk = 0;
#pragma unroll
      for (int k = 0; k < 4; ++k) {
        const float* p = c1 + ((j0 + k) * kN + n) * 3;
        const float r0 = p[0], r1 = p[1], r2 = p[2];
        const float rr = rr_exact(r0, r1, r2);
        const float dot = __fadd_rn(
            __fadd_rn(__fmul_rn(qxs[i], r0), __fmul_rn(qys[i], r1)),
            __fmul_rn(qzs[i], r2));
        const float dc = __fmaf_rn(-2.0f, dot, __fadd_rn(qqs[i], rr));
        if (dc < best) { best = dc; kk = k; }
      }
      out[(q0 + i) * kN + n] = j0 + kk;
      out[kL2 * kN + (q0 + i) * kN + n] = n;
    }
  }
}

extern "C" void kernel_launch(void* const* d_in, const int* in_sizes, int n_in,
                              void* d_out, int out_size, void* d_ws, size_t ws_size,
                              hipStream_t stream) {
  const float* c1 = (const float*)d_in[0];
  const float* c2 = (const float*)d_in[1];
  int* out = (int*)d_out;
  if (d_ws != nullptr && ws_size >= kWsBytes) {
    int* cellStart = (int*)d_ws;
    float4* pts = (float4*)((char*)d_ws + kOffPts);
    int* pidx = (int*)((char*)d_ws + kOffIdx);
    bin_kernel<<<dim3(kN), dim3(1024), 0, stream>>>(c1, cellStart, pts, pidx);
    grid_nn_kernel<<<dim3(kL2 * kN * 8 / 256), dim3(256), 0, stream>>>(
        cellStart, pts, pidx, c2, out);
  } else {
    dim3 grid(kL2 / kQPerBlock, kN);
    nearest_kernel_lds<<<grid, dim3(256), 0, stream>>>(c1, c2, out);
  }
}